// Round 4
// baseline (295.233 us; speedup 1.0000x reference)
//
#include <hip/hip_runtime.h>
#include <cmath>

// PSNR + 3D-SSIM, pred/gt (N=4, C=16->D, H=512, W=512) f32.
// R12: all three blur passes on the MATRIX pipe (MfmaUtil was 0 while
// VALU+LDS were jointly saturated). Per 16x16 tile, per slice, per channel:
//   H:  T^T = S^T(26pad32 x 32) x Gh^T(32x16)   1 MFMA per 16-col tile (x2)
//   W:  O   = T(16x32) x Gw(32x16)              1 MFMA (A-frag = H output
//       registers directly: C row=4hi+reg matches k-slot sigma=4hi+(i&3)+16(i>>2))
//   D:  Out = WL(16x32pad) x Ostack^T(32x256px) 16 MFMA epilogue per wave
// Coefficient operands are constant per-lane fragments, host-packed into
// d_ws (consistent-k trick: any k-permutation is legal if A and B agree).
// Ostack [ch][px][d16] f16 with block-bit XOR swizzle (d^8*(px>>6&1)),
// compensated on the read side by address, so sigma stays global.
// Waves = channels in the slice loop; waves = px-quadrants in the epilogue.
// 2 barriers/slice; prefetch issued AFTER B2 (barrier drains vmcnt).

#define NB 4
#define DD 16
#define HH 512
#define WW 512
#define SLICE (HH * WW)
#define VOL (DD * SLICE)
#define C1F 0.0001f
#define C2F 0.0009f

#define TH 16
#define TW 16
#define NTHR 256

typedef _Float16 h8 __attribute__((ext_vector_type(8)));
typedef float f4 __attribute__((ext_vector_type(4)));

__device__ inline f4 mfma16(uint4 a, uint4 b, f4 c) {
  return __builtin_amdgcn_mfma_f32_16x16x32_f16(
      __builtin_bit_cast(h8, a), __builtin_bit_cast(h8, b), c, 0, 0, 0);
}
__device__ inline unsigned pkh(float a, float b) {
  return __builtin_bit_cast(unsigned, __builtin_amdgcn_cvt_pkrtz(a, b));
}
__device__ inline int iclamp(int v, int lo, int hi) {
  return v < lo ? lo : (v > hi ? hi : v);
}

__device__ inline float block_sum256(float v) {
#pragma unroll
  for (int o = 32; o > 0; o >>= 1) v += __shfl_down(v, o, 64);
  __shared__ float r[4];
  if ((threadIdx.x & 63) == 0) r[threadIdx.x >> 6] = v;
  __syncthreads();
  float out = 0.f;
  if (threadIdx.x == 0) {
#pragma unroll
    for (int i = 0; i < 4; ++i) out += r[i];
  }
  __syncthreads();
  return out;
}

__global__ void zero_acc_k(float* acc) {
  if (threadIdx.x < 8) acc[threadIdx.x] = 0.f;
}

// sd layout: [ch4][c32][r40] f16 (r contiguous; r26..39 & c26..31 stay zero)
//   u32 index = ch*640 + c*20 + rp ; uint4 index = ch*160 + c*5 + hi
// ost layout: [ch4][px256][d16] f16, d-quad stored at Q^(2*(px>>6&1))
__global__ __launch_bounds__(NTHR, 3) void fused_k(
    const float* __restrict__ pred, const float* __restrict__ gt,
    float* __restrict__ acc, const uint4* __restrict__ tabs) {
  __shared__ _Float16 sd[4 * 32 * 40];     // 10240 B
  __shared__ _Float16 ost[4 * 256 * 16];   // 32768 B
  __shared__ uint4 zzq;                    // 16 B of zeros (K-pad reads)

  int b = blockIdx.x;
  int tile = b & 1023;               // 32 h-tiles x 32 w-tiles
  int n = b >> 10;
  int th0 = (tile >> 5) * TH;
  int tw0 = (tile & 31) * TW;
  int t = threadIdx.x;
  int lane = t & 63, wv = t >> 6;
  int lo = lane & 15, hi = lane >> 4;

  // constant fragments (host-packed, consistent sigma on both operands)
  uint4 bh = tabs[lane];          // Gh^T: B[k=r=8hi+i][n=mout=lo]
  uint4 gwt = tabs[64 + lane];    // Gw:   B[k=c=sigma(hi,i)][n=w=lo]
  uint4 wlf = tabs[128 + lane];   // WL:   A[m=dout=lo][k=d=8hi+i]

  // zero-init sd (pads must be 0) + zz
  unsigned* sdw = (unsigned*)sd;
#pragma unroll
  for (int i = 0; i < 10; ++i) sdw[t + i * 256] = 0;
  if (t == 0) zzq = make_uint4(0, 0, 0, 0);

  // ---- stage metadata, slot 0 (item t, SIT=338)
  int rp0 = t / 26, x0 = t - rp0 * 26;
  int gx0 = iclamp(tw0 + x0 - 5, 0, WW - 1);
  int go0a = iclamp(th0 + 2 * rp0 - 5, 0, HH - 1) * WW + gx0;
  int go0b = iclamp(th0 + 2 * rp0 - 4, 0, HH - 1) * WW + gx0;
  int w0 = x0 * 20 + rp0;
  bool ox0 = (x0 >= 5) && (x0 < 21);
  float o0a = (ox0 && rp0 >= 3 && rp0 <= 10) ? 1.f : 0.f;
  float o0b = (ox0 && rp0 >= 2 && rp0 <= 9) ? 1.f : 0.f;
  // slot 1 (items 256..337 -> threads 174..255)
  int i1 = t + 82;
  bool has2 = (i1 >= 256);
  int rp1 = i1 / 26, x1 = i1 - rp1 * 26;
  int gx1 = iclamp(tw0 + x1 - 5, 0, WW - 1);
  int go1a = iclamp(th0 + 2 * rp1 - 5, 0, HH - 1) * WW + gx1;
  int go1b = iclamp(th0 + 2 * rp1 - 4, 0, HH - 1) * WW + gx1;
  int w1 = x1 * 20 + rp1;
  bool ox1 = (x1 >= 5) && (x1 < 21);
  float o1a = (ox1 && rp1 >= 3 && rp1 <= 10) ? 1.f : 0.f;
  float o1b = (ox1 && rp1 >= 2 && rp1 <= 9) ? 1.f : 0.f;

  const float* pb = pred + (size_t)n * VOL;
  const float* qb = gt + (size_t)n * VOL;

  // prefetch slice 0
  float p0a = pb[go0a], p0b = pb[go0b], q0a = qb[go0a], q0b = qb[go0b];
  float p1a = 0.f, p1b = 0.f, q1a = 0.f, q1b = 0.f;
  if (has2) { p1a = pb[go1a]; p1b = pb[go1b]; q1a = qb[go1a]; q1b = qb[go1b]; }

  // O-write addressing (u64 units): ch*1024 + px*4 + Q', px = 64hi+16reg+lo
  int owb = wv * 1024 + (64 * hi + lo) * 4;
  int qx = 2 * (hi & 1);           // Q' = (d>>2) ^ qx
  const uint4* sdq = (const uint4*)sd;
  int fr0 = wv * 160 + lo * 5 + hi;
  int fr1 = wv * 160 + (lo + 16) * 5 + hi;
  f4 z4 = {0.f, 0.f, 0.f, 0.f};

  float psnr = 0.f;
  float oe0, oe1, oe2, oe3;                      // even-d O values
  unsigned pA0, pA1, pA2, pA3, pB0, pB1, pB2, pB3;  // packed d-pairs
  oe0 = oe1 = oe2 = oe3 = 0.f;
  pA0 = pA1 = pA2 = pA3 = pB0 = pB1 = pB2 = pB3 = 0u;

  __syncthreads();   // zero-init visible before first stage

#pragma unroll 1
  for (int d = 0; d < DD; ++d) {
    // ---- stage slice d (4 b32 writes per item: S,D,S2,D2 row-pairs)
    {
      float SA = p0a + q0a, DA = p0a - q0a;
      float SB = p0b + q0b, DB = p0b - q0b;
      float dA = DA * DA, dB = DB * DB;
      psnr = fmaf(o0a, dA, psnr);
      psnr = fmaf(o0b, dB, psnr);
      sdw[w0]        = pkh(SA, SB);
      sdw[640 + w0]  = pkh(DA, DB);
      sdw[1280 + w0] = pkh(SA * SA, SB * SB);
      sdw[1920 + w0] = pkh(dA, dB);
    }
    if (has2) {
      float SA = p1a + q1a, DA = p1a - q1a;
      float SB = p1b + q1b, DB = p1b - q1b;
      float dA = DA * DA, dB = DB * DB;
      psnr = fmaf(o1a, dA, psnr);
      psnr = fmaf(o1b, dB, psnr);
      sdw[w1]        = pkh(SA, SB);
      sdw[640 + w1]  = pkh(DA, DB);
      sdw[1280 + w1] = pkh(SA * SA, SB * SB);
      sdw[1920 + w1] = pkh(dA, dB);
    }
    __syncthreads();   // B1: sd ready

    // ---- A-fragments for H (this wave's channel): 2x ds_read_b128
    uint4 fa0 = sdq[fr0];
    uint4 fa1 = sdq[fr1];
    __syncthreads();   // B2: all frag reads done -> next stage safe
                       // (barrier waits lgkmcnt -> fa0/fa1 in regs)

    // ---- prefetch slice d+1 (after B2 so barrier vmcnt-drain can't stall it)
    if (d < DD - 1) {
      const float* P = pb + (size_t)(d + 1) * SLICE;
      const float* Q = qb + (size_t)(d + 1) * SLICE;
      p0a = P[go0a]; p0b = P[go0b]; q0a = Q[go0a]; q0b = Q[go0b];
      if (has2) { p1a = P[go1a]; p1b = P[go1b]; q1a = Q[go1a]; q1b = Q[go1b]; }
    }

    // ---- H: T^T tiles (c=0..15, 16..31); W: O = T x Gw
    f4 t0 = mfma16(fa0, bh, z4);
    f4 t1 = mfma16(fa1, bh, z4);
    uint4 ta = make_uint4(pkh(t0.x, t0.y), pkh(t0.z, t0.w),
                          pkh(t1.x, t1.y), pkh(t1.z, t1.w));
    f4 o = mfma16(ta, gwt, z4);

    // ---- pack O across 4 slices -> one ds_write_b64 per reg per quad
    if ((d & 1) == 0) {
      oe0 = o.x; oe1 = o.y; oe2 = o.z; oe3 = o.w;
    } else if ((d & 2) == 0) {
      pA0 = pkh(oe0, o.x); pA1 = pkh(oe1, o.y);
      pA2 = pkh(oe2, o.z); pA3 = pkh(oe3, o.w);
    } else {
      pB0 = pkh(oe0, o.x); pB1 = pkh(oe1, o.y);
      pB2 = pkh(oe2, o.z); pB3 = pkh(oe3, o.w);
      int Qp = (d >> 2) ^ qx;
      uint2* op = (uint2*)ost;
      op[owb + Qp]       = make_uint2(pA0, pB0);
      op[owb + 64 + Qp]  = make_uint2(pA1, pB1);
      op[owb + 128 + Qp] = make_uint2(pA2, pB2);
      op[owb + 192 + Qp] = make_uint2(pA3, pB3);
    }
  }
  __syncthreads();   // Ostack complete (cross-wave)

  // ---- epilogue: D-GEMM (A=WL const) + SSIM; waves own px-quadrants
  const uint4* oq = (const uint4*)ost;
  int bnt = wv & 1;                 // (px>>6)&1 for px = 16*nt+lo, nt=4wv+q
  int blk = (hi < 2) ? (hi ^ bnt) : 0;
  bool real = (hi < 2);
  float ssum = 0.f;
#pragma unroll
  for (int q = 0; q < 4; ++q) {
    int nt = 4 * wv + q;
    int bidx = (16 * nt + lo) * 2 + blk;
    const uint4* bp0 = real ? &oq[bidx] : &zzq;
    const uint4* bp1 = real ? &oq[512 + bidx] : &zzq;
    const uint4* bp2 = real ? &oq[1024 + bidx] : &zzq;
    const uint4* bp3 = real ? &oq[1536 + bidx] : &zzq;
    f4 cS = mfma16(wlf, *bp0, z4);
    f4 cD = mfma16(wlf, *bp1, z4);
    f4 cS2 = mfma16(wlf, *bp2, z4);
    f4 cD2 = mfma16(wlf, *bp3, z4);
#pragma unroll
    for (int r = 0; r < 4; ++r) {
      float Sb = cS[r], Db = cD[r], B1 = cS2[r], B2 = cD2[r];
      float SS = Sb * Sb, DDm = Db * Db;
      float m12_2 = (SS - DDm) * 0.5f;
      float msq = (SS + DDm) * 0.5f;
      float Epq = (B1 - B2) * 0.25f;
      float Esum = (B1 + B2) * 0.5f;
      float sig12_2 = 2.f * Epq - m12_2;
      float svar = Esum - msq;
      float num = (m12_2 + C1F) * (sig12_2 + C2F);
      float den = (msq + C1F) * (svar + C2F);
      ssum += num / den;
    }
  }
  float bs = block_sum256(ssum);
  if (t == 0) atomicAdd(&acc[4 + n], bs);
  float bp = block_sum256(psnr);
  if (t == 0) atomicAdd(&acc[n], bp);
}

__global__ void final_k(const float* __restrict__ acc, float* __restrict__ out) {
  if (threadIdx.x == 0 && blockIdx.x == 0) {
    double psnr = 0.0, ssim = 0.0;
    for (int n = 0; n < NB; ++n) {
      double mse = (double)acc[n] / (double)VOL;
      psnr += 10.0 * log10(1.0 / mse);
      ssim += (double)acc[4 + n] / (double)VOL;
    }
    out[0] = (float)psnr;
    out[1] = (float)ssim;
    out[2] = (float)NB;
  }
}

// host f32 -> f16 (RNE)
static unsigned short f2h(float f) {
  union { float f; unsigned u; } v; v.f = f;
  unsigned u = v.u;
  unsigned s = (u >> 16) & 0x8000u;
  int e = (int)((u >> 23) & 0xff) - 127 + 15;
  unsigned m = u & 0x7fffffu;
  if (e <= 0) return (unsigned short)s;
  if (e >= 31) return (unsigned short)(s | 0x7c00u);
  unsigned h = ((unsigned)e << 10) | (m >> 13);
  unsigned rem = m & 0x1fffu;
  if (rem > 0x1000u || (rem == 0x1000u && (h & 1u))) h++;
  return (unsigned short)(s | h);
}
static float h2f(unsigned short h) {
  unsigned se = (h >> 10) & 0x1f, m = h & 0x3ffu, s = ((unsigned)h & 0x8000u) << 16;
  union { unsigned u; float f; } v;
  if (se == 0) { v.u = s; return v.f; }
  v.u = s | ((se - 15 + 127) << 23) | (m << 13);
  return v.f;
}

static unsigned s_tabs[192 * 4];   // 3 KB: Bh | Gw | WL per-lane fragments
static bool s_init = false;

extern "C" void kernel_launch(void* const* d_in, const int* in_sizes, int n_in,
                              void* d_out, int out_size, void* d_ws, size_t ws_size,
                              hipStream_t stream) {
  const float* pred = (const float*)d_in[0];
  const float* gt = (const float*)d_in[1];
  float* acc = (float*)d_ws;    // 8 floats @ +0; tables @ +64

  if (!s_init) {
    double tt[11], s = 0.0;
    for (int i = 0; i < 11; ++i) {
      double x = i - 5;
      tt[i] = exp(-(x * x) / 4.5);
      s += tt[i];
    }
    float g[11];
    for (int i = 0; i < 11; ++i) g[i] = (float)(tt[i] / s);
    // f16 taps, renormalized so f16 values sum exactly to 1
    unsigned short hg[11];
    for (int i = 0; i < 11; ++i) hg[i] = f2h(g[i]);
    for (int pass = 0; pass < 3; ++pass) {
      double sum = 0.0;
      for (int i = 0; i < 11; ++i) sum += (double)h2f(hg[i]);
      hg[5] = f2h((float)((double)h2f(hg[5]) + (1.0 - sum)));
    }
    // clamp-folded D weights wl[d][o]; f16 per-dout renorm -> wlh[o][d]
    float wl[DD][DD];
    for (int o = 0; o < DD; ++o)
      for (int d = 0; d < DD; ++d) {
        float w = 0.f;
        for (int k = 0; k < 11; ++k) {
          int j = o + k - 5;
          j = j < 0 ? 0 : (j > 15 ? 15 : j);
          if (j == d) w += g[k];
        }
        wl[d][o] = w;
      }
    unsigned short wlh[DD][DD];
    for (int o = 0; o < DD; ++o) {
      int dmx = 0;
      for (int d = 0; d < DD; ++d) {
        wlh[o][d] = f2h(wl[d][o]);
        if (wl[d][o] > wl[dmx][o]) dmx = d;
      }
      for (int pass = 0; pass < 3; ++pass) {
        double sum = 0.0;
        for (int d = 0; d < DD; ++d) sum += (double)h2f(wlh[o][d]);
        wlh[o][dmx] = f2h((float)((double)h2f(wlh[o][dmx]) + (1.0 - sum)));
      }
    }
    for (int l = 0; l < 64; ++l) {
      int lo = l & 15, hi = l >> 4;
      unsigned short v[8];
      // Bh: B[k=r=8hi+i][n=mout=lo] = g[r - lo]
      for (int i = 0; i < 8; ++i) {
        int idx = 8 * hi + i - lo;
        v[i] = (idx >= 0 && idx <= 10) ? hg[idx] : 0;
      }
      for (int k = 0; k < 4; ++k)
        s_tabs[l * 4 + k] = (unsigned)v[2 * k] | ((unsigned)v[2 * k + 1] << 16);
      // Gw: B[k=c=4hi+(i&3)+16(i>>2)][n=w=lo] = g[c - lo]
      for (int i = 0; i < 8; ++i) {
        int c = 4 * hi + (i & 3) + 16 * (i >> 2);
        int idx = c - lo;
        v[i] = (idx >= 0 && idx <= 10) ? hg[idx] : 0;
      }
      for (int k = 0; k < 4; ++k)
        s_tabs[(64 + l) * 4 + k] = (unsigned)v[2 * k] | ((unsigned)v[2 * k + 1] << 16);
      // WL: A[m=dout=lo][k=d=8hi+i]; zero for hi>=2 (K pad)
      for (int i = 0; i < 8; ++i)
        v[i] = (hi < 2) ? wlh[lo][8 * hi + i] : 0;
      for (int k = 0; k < 4; ++k)
        s_tabs[(128 + l) * 4 + k] = (unsigned)v[2 * k] | ((unsigned)v[2 * k + 1] << 16);
    }
    s_init = true;
  }

  hipMemcpyAsync((char*)d_ws + 64, s_tabs, sizeof(s_tabs),
                 hipMemcpyHostToDevice, stream);
  zero_acc_k<<<1, 64, 0, stream>>>(acc);
  fused_k<<<NB * 1024, NTHR, 0, stream>>>(pred, gt, acc,
                                          (const uint4*)((char*)d_ws + 64));
  final_k<<<1, 1, 0, stream>>>(acc, (float*)d_out);
}